// Round 1
// baseline (231.146 us; speedup 1.0000x reference)
//
#include <hip/hip_runtime.h>

#define DETN 128
#define NPIX (DETN * DETN)        // 16384 rays per projection
#define VDIM 128
#define NVOX (VDIM * VDIM * VDIM) // 2097152
#define NWORDS (NVOX / 32)        // 65536 words = 256 KiB per volume
#define NSAMP 512

// ---------------------------------------------------------------------------
// Backprojection: one thread per ray. Sets bits in a bit-packed 128^3 volume.
// blockIdx.y = projection index p in [0, 2B): batch = p>>1, view = p&1 (0=F,1=L)
// ---------------------------------------------------------------------------
__global__ __launch_bounds__(256) void bp_kernel(
    const float* __restrict__ predF, const float* __restrict__ predL,
    const float* __restrict__ srcF,  const float* __restrict__ srcL,
    const float* __restrict__ tgtF,  const float* __restrict__ tgtL,
    const float* __restrict__ Ainv,  const float* __restrict__ tinv,
    unsigned int* __restrict__ flags)
{
    const int p     = blockIdx.y;
    const int view  = p & 1;
    const int batch = p >> 1;
    const int ray   = blockIdx.x * blockDim.x + threadIdx.x;
    if (ray >= NPIX) return;

    const float* mask = (view ? predL : predF) + batch * NPIX;
    if (!(mask[ray] > 0.5f)) return;   // inactive ray: contributes nothing

    const float* src = view ? srcL : srcF;
    const float* tgt = (view ? tgtL : tgtF) + ray * 3;

    const float sx = src[0], sy = src[1], sz = src[2];
    float dx = tgt[0] - sx, dy = tgt[1] - sy, dz = tgt[2] - sz;
    const float len = sqrtf(dx * dx + dy * dy + dz * dz);
    const float inv = 1.0f / (len + 1e-8f);
    dx *= inv; dy *= inv; dz *= inv;

    // voxel coords are affine in t:  q(t) = qc + qd * t
    const float a00 = Ainv[0], a01 = Ainv[1], a02 = Ainv[2];
    const float a10 = Ainv[3], a11 = Ainv[4], a12 = Ainv[5];
    const float a20 = Ainv[6], a21 = Ainv[7], a22 = Ainv[8];
    const float qcx = a00 * sx + a01 * sy + a02 * sz + tinv[0];
    const float qcy = a10 * sx + a11 * sy + a12 * sz + tinv[1];
    const float qcz = a20 * sx + a21 * sy + a22 * sz + tinv[2];
    const float qdx = a00 * dx + a01 * dy + a02 * dz;
    const float qdy = a10 * dx + a11 * dy + a12 * dz;
    const float qdz = a20 * dx + a21 * dy + a22 * dz;

    const float tmax = len * 2.5f;
    const float dt   = tmax * (1.0f / 511.0f);   // t_k = k * dt

    // slab intersection (with margin) to skip the ~90% out-of-bounds samples
    float tlo = 0.0f, thi = tmax;
    {
        const float c[3] = {qcx, qcy, qcz};
        const float d[3] = {qdx, qdy, qdz};
        #pragma unroll
        for (int j = 0; j < 3; ++j) {
            if (fabsf(d[j]) < 1e-8f) {
                if (c[j] < -0.6f || c[j] > 127.6f) thi = -1.0f;  // empty
            } else {
                const float ta = (-0.6f  - c[j]) / d[j];
                const float tb = (127.6f - c[j]) / d[j];
                tlo = fmaxf(tlo, fminf(ta, tb));
                thi = fminf(thi, fmaxf(ta, tb));
            }
        }
    }
    if (tlo > thi) return;
    const int klo = max(0, (int)ceilf(tlo / dt));
    const int khi = min(NSAMP - 1, (int)floorf(thi / dt));

    unsigned int* __restrict__ vol = flags + (size_t)p * NWORDS;
    for (int k = klo; k <= khi; ++k) {
        const float t  = (float)k * dt;
        const float qx = fmaf(qdx, t, qcx);
        const float qy = fmaf(qdy, t, qcy);
        const float qz = fmaf(qdz, t, qcz);
        const int ix = (int)rintf(qx);   // ties-to-even, matches jnp.round
        const int iy = (int)rintf(qy);
        const int iz = (int)rintf(qz);
        if ((unsigned)ix < (unsigned)VDIM && (unsigned)iy < (unsigned)VDIM &&
            (unsigned)iz < (unsigned)VDIM) {
            const int lin = (ix << 14) | (iy << 7) | iz;
            atomicOr(&vol[lin >> 5], 1u << (lin & 31));
        }
    }
}

// ---------------------------------------------------------------------------
// Loss: p = sigmoid(k), k = volF + volL in {0,1,2}.
// BCE contribution per voxel/batch = -log(1-p[k]) - g*k   (since logit = k)
// result = sum / (NVOX * B)
// ---------------------------------------------------------------------------
__global__ __launch_bounds__(256) void loss_kernel(
    const unsigned int* __restrict__ flags,
    const float* __restrict__ gt,
    float* __restrict__ out, int B, float scale)
{
    float acc = 0.0f;
    const int stride = gridDim.x * blockDim.x;
    for (int v = blockIdx.x * blockDim.x + threadIdx.x; v < NVOX; v += stride) {
        const float g = gt[v];
        const int w = v >> 5;
        const int b = v & 31;
        for (int i = 0; i < B; ++i) {
            const unsigned f = flags[(size_t)(2 * i)     * NWORDS + w];
            const unsigned l = flags[(size_t)(2 * i + 1) * NWORDS + w];
            const int k = (int)((f >> b) & 1u) + (int)((l >> b) & 1u);
            // -log(1-sigmoid(k)) for k=0,1,2
            const float negl1mp =
                (k == 0) ? 0.6931471806f : ((k == 1) ? 1.3132616875f : 2.1269280110f);
            acc += negl1mp - g * (float)k;
        }
    }

    // wave reduce (64 lanes)
    #pragma unroll
    for (int off = 32; off > 0; off >>= 1) acc += __shfl_down(acc, off);

    __shared__ float smem[4];   // 256 threads = 4 waves
    const int wid  = threadIdx.x >> 6;
    const int lane = threadIdx.x & 63;
    if (lane == 0) smem[wid] = acc;
    __syncthreads();
    if (threadIdx.x == 0) {
        const float tot = smem[0] + smem[1] + smem[2] + smem[3];
        atomicAdd(out, tot * scale);
    }
}

extern "C" void kernel_launch(void* const* d_in, const int* in_sizes, int n_in,
                              void* d_out, int out_size, void* d_ws, size_t ws_size,
                              hipStream_t stream) {
    const float* predF = (const float*)d_in[0];
    const float* predL = (const float*)d_in[1];
    const float* srcF  = (const float*)d_in[2];
    const float* tgtF  = (const float*)d_in[3];
    const float* srcL  = (const float*)d_in[4];
    const float* tgtL  = (const float*)d_in[5];
    const float* gt    = (const float*)d_in[6];
    const float* Ainv  = (const float*)d_in[7];
    const float* tinv  = (const float*)d_in[8];

    const int B = in_sizes[0] / NPIX;               // = 2
    unsigned int* flags = (unsigned int*)d_ws;      // 2B bit-volumes, 256 KiB each

    hipMemsetAsync(flags, 0, (size_t)(2 * B) * NWORDS * sizeof(unsigned int), stream);
    hipMemsetAsync(d_out, 0, sizeof(float), stream);

    dim3 gridBp(NPIX / 256, 2 * B);
    bp_kernel<<<gridBp, 256, 0, stream>>>(predF, predL, srcF, srcL,
                                          tgtF, tgtL, Ainv, tinv, flags);

    const float scale = 1.0f / ((float)NVOX * (float)B);
    loss_kernel<<<2048, 256, 0, stream>>>(flags, gt, (float*)d_out, B, scale);
}

// Round 2
// 114.830 us; speedup vs baseline: 2.0129x; 2.0129x over previous
//
#include <hip/hip_runtime.h>

#define DETN 128
#define NPIX (DETN * DETN)        // 16384 rays per projection
#define VDIM 128
#define NVOX (VDIM * VDIM * VDIM) // 2097152
#define NWORDS (NVOX / 32)        // 65536 words = 256 KiB per bit-volume
#define NSAMP 512
#define SPLITK 4

// ---------------------------------------------------------------------------
// Backprojection, dual-packed bitmaps + run-merged atomics.
//   frontal (view 0): z-packed  word = ix<<9 | iy<<2 | iz>>5, bit iz&31
//   lateral (view 1): x-packed  word = iz<<9 | iy<<2 | ix>>5, bit ix&31
// Rays march along their packed axis (~2.5 vox/sample) so ~13 consecutive
// samples share a word -> accumulate bits in a register, one atomicOr per run.
// blockIdx.y = projection p in [0,2B): batch=p>>1, view=p&1.
// blockIdx.z = k-segment (SPLITK-way split of the in-bounds sample range;
//              straddling runs just issue an extra atomicOr - safe).
// ---------------------------------------------------------------------------
__global__ __launch_bounds__(256) void bp_kernel(
    const float* __restrict__ predF, const float* __restrict__ predL,
    const float* __restrict__ srcF,  const float* __restrict__ srcL,
    const float* __restrict__ tgtF,  const float* __restrict__ tgtL,
    const float* __restrict__ Ainv,  const float* __restrict__ tinv,
    unsigned int* __restrict__ flags)
{
    const int p     = blockIdx.y;
    const int view  = p & 1;
    const int batch = p >> 1;
    const int ray   = blockIdx.x * blockDim.x + threadIdx.x;

    const float* mask = (view ? predL : predF) + batch * NPIX;
    if (!(mask[ray] > 0.5f)) return;   // inactive ray

    const float* src = view ? srcL : srcF;
    const float* tgt = (view ? tgtL : tgtF) + ray * 3;

    const float sx = src[0], sy = src[1], sz = src[2];
    float dx = tgt[0] - sx, dy = tgt[1] - sy, dz = tgt[2] - sz;
    const float len = sqrtf(dx * dx + dy * dy + dz * dz);
    const float inv = 1.0f / (len + 1e-8f);
    dx *= inv; dy *= inv; dz *= inv;

    // voxel coords affine in t:  q(t) = qc + qd * t
    const float a00 = Ainv[0], a01 = Ainv[1], a02 = Ainv[2];
    const float a10 = Ainv[3], a11 = Ainv[4], a12 = Ainv[5];
    const float a20 = Ainv[6], a21 = Ainv[7], a22 = Ainv[8];
    const float qcx = a00 * sx + a01 * sy + a02 * sz + tinv[0];
    const float qcy = a10 * sx + a11 * sy + a12 * sz + tinv[1];
    const float qcz = a20 * sx + a21 * sy + a22 * sz + tinv[2];
    const float qdx = a00 * dx + a01 * dy + a02 * dz;
    const float qdy = a10 * dx + a11 * dy + a12 * dz;
    const float qdz = a20 * dx + a21 * dy + a22 * dz;

    const float tmax = len * 2.5f;
    const float dt   = tmax * (1.0f / 511.0f);   // t_k = k * dt

    // slab intersection (with margin) to skip the ~90% out-of-bounds samples
    float tlo = 0.0f, thi = tmax;
    {
        const float c[3] = {qcx, qcy, qcz};
        const float d[3] = {qdx, qdy, qdz};
        #pragma unroll
        for (int j = 0; j < 3; ++j) {
            if (fabsf(d[j]) < 1e-8f) {
                if (c[j] < -0.6f || c[j] > 127.6f) thi = -1.0f;  // empty
            } else {
                const float ta = (-0.6f  - c[j]) / d[j];
                const float tb = (127.6f - c[j]) / d[j];
                tlo = fmaxf(tlo, fminf(ta, tb));
                thi = fminf(thi, fmaxf(ta, tb));
            }
        }
    }
    if (tlo > thi) return;
    const int klo = max(0, (int)ceilf(tlo / dt));
    const int khi = min(NSAMP - 1, (int)floorf(thi / dt));

    // this thread's k-segment
    const int n   = khi - klo + 1;
    const int per = (n + SPLITK - 1) / SPLITK;
    const int k0  = klo + (int)blockIdx.z * per;
    const int k1  = min(khi, k0 + per - 1);
    if (k0 > khi) return;

    unsigned int* __restrict__ vol = flags + (size_t)p * NWORDS;
    int      curw = -1;
    unsigned bits = 0;
    for (int k = k0; k <= k1; ++k) {
        const float t  = (float)k * dt;
        const float qx = fmaf(qdx, t, qcx);
        const float qy = fmaf(qdy, t, qcy);
        const float qz = fmaf(qdz, t, qcz);
        const int ix = (int)rintf(qx);   // ties-to-even, matches jnp.round
        const int iy = (int)rintf(qy);
        const int iz = (int)rintf(qz);
        if ((unsigned)ix < (unsigned)VDIM && (unsigned)iy < (unsigned)VDIM &&
            (unsigned)iz < (unsigned)VDIM) {
            const int maj = view ? iz : ix;   // slow axis
            const int pk  = view ? ix : iz;   // packed (fast) axis
            const int w   = (maj << 9) | (iy << 2) | (pk >> 5);
            const unsigned bit = 1u << (pk & 31);
            if (w == curw) {
                bits |= bit;
            } else {
                if (curw >= 0) atomicOr(&vol[curw], bits);
                curw = w; bits = bit;
            }
        }
    }
    if (curw >= 0) atomicOr(&vol[curw], bits);
}

// ---------------------------------------------------------------------------
// Bit-transpose: lateral x-packed volume -> z-packed. One thread per output
// word; the 32 gathered input words live in a 256 KiB L2-resident bitmap.
// Every output word is fully written (no memset needed on latz).
// ---------------------------------------------------------------------------
__global__ __launch_bounds__(256) void transpose_kernel(
    const unsigned int* __restrict__ flags,   // 2B interleaved volumes
    unsigned int* __restrict__ latz, int B)
{
    const int idx = blockIdx.x * blockDim.x + threadIdx.x;  // over B*NWORDS
    const int b = idx >> 16;              // NWORDS = 65536
    const int w = idx & (NWORDS - 1);     // z-packed word: x<<9 | y<<2 | Z
    if (b >= B) return;
    const int x = w >> 9;
    const int y = (w >> 2) & 127;
    const int Z = w & 3;
    const unsigned int* __restrict__ src = flags + (size_t)(2 * b + 1) * NWORDS;
    const int base = (y << 2) | (x >> 5);
    const int sh   = x & 31;
    unsigned out = 0;
    #pragma unroll
    for (int zz = 0; zz < 32; ++zz) {
        const unsigned m = src[(((Z << 5) + zz) << 9) | base];
        out |= ((m >> sh) & 1u) << zz;
    }
    latz[(size_t)b * NWORDS + w] = out;
}

// ---------------------------------------------------------------------------
// Loss: one thread per 32-voxel word. k = bitF + bitL in {0,1,2}; logit = k so
// per-voxel BCE = -log(1-sigmoid(k)) - g*k. Constant term via popcounts.
// ---------------------------------------------------------------------------
__global__ __launch_bounds__(256) void loss_kernel(
    const unsigned int* __restrict__ flags,
    const unsigned int* __restrict__ latz,
    const float* __restrict__ gt,
    float* __restrict__ out, int B, float scale)
{
    const int w = blockIdx.x * blockDim.x + threadIdx.x;
    float acc = 0.0f;
    if (w < NWORDS) {
        const float4* __restrict__ g4 = (const float4*)(gt + (size_t)w * 32);
        float g[32];
        #pragma unroll
        for (int q = 0; q < 8; ++q) {
            const float4 v = g4[q];
            g[4 * q + 0] = v.x; g[4 * q + 1] = v.y;
            g[4 * q + 2] = v.z; g[4 * q + 3] = v.w;
        }
        for (int b = 0; b < B; ++b) {
            const unsigned F = flags[(size_t)(2 * b) * NWORDS + w];
            const unsigned L = latz[(size_t)b * NWORDS + w];
            const int n2 = __popc(F & L);
            const int n1 = __popc(F | L) - n2;
            const int n0 = 32 - n1 - n2;
            acc += 0.6931471806f * (float)n0 + 1.3132616875f * (float)n1 +
                   2.1269280110f * (float)n2;
            float s = 0.0f;
            #pragma unroll
            for (int i = 0; i < 32; ++i) {
                s += g[i] * (float)(((F >> i) & 1u) + ((L >> i) & 1u));
            }
            acc -= s;
        }
    }

    // wave reduce (64 lanes)
    #pragma unroll
    for (int off = 32; off > 0; off >>= 1) acc += __shfl_down(acc, off);

    __shared__ float smem[4];   // 256 threads = 4 waves
    const int wid  = threadIdx.x >> 6;
    const int lane = threadIdx.x & 63;
    if (lane == 0) smem[wid] = acc;
    __syncthreads();
    if (threadIdx.x == 0) {
        const float tot = smem[0] + smem[1] + smem[2] + smem[3];
        atomicAdd(out, tot * scale);
    }
}

extern "C" void kernel_launch(void* const* d_in, const int* in_sizes, int n_in,
                              void* d_out, int out_size, void* d_ws, size_t ws_size,
                              hipStream_t stream) {
    const float* predF = (const float*)d_in[0];
    const float* predL = (const float*)d_in[1];
    const float* srcF  = (const float*)d_in[2];
    const float* tgtF  = (const float*)d_in[3];
    const float* srcL  = (const float*)d_in[4];
    const float* tgtL  = (const float*)d_in[5];
    const float* gt    = (const float*)d_in[6];
    const float* Ainv  = (const float*)d_in[7];
    const float* tinv  = (const float*)d_in[8];

    const int B = in_sizes[0] / NPIX;               // = 2
    unsigned int* flags = (unsigned int*)d_ws;      // 2B volumes, 256 KiB each
    unsigned int* latz  = flags + (size_t)(2 * B) * NWORDS;  // B transposed

    hipMemsetAsync(flags, 0, (size_t)(2 * B) * NWORDS * sizeof(unsigned int), stream);
    hipMemsetAsync(d_out, 0, sizeof(float), stream);

    dim3 gridBp(NPIX / 256, 2 * B, SPLITK);
    bp_kernel<<<gridBp, 256, 0, stream>>>(predF, predL, srcF, srcL,
                                          tgtF, tgtL, Ainv, tinv, flags);

    transpose_kernel<<<(B * NWORDS) / 256, 256, 0, stream>>>(flags, latz, B);

    const float scale = 1.0f / ((float)NVOX * (float)B);
    loss_kernel<<<NWORDS / 256, 256, 0, stream>>>(flags, latz, gt,
                                                  (float*)d_out, B, scale);
}